// Round 3
// baseline (32.240 us; speedup 1.0000x reference)
//
#include <hip/hip_runtime.h>

// a,p,n: [16,3,512,512] f32. H=W=512; window 128x128 stride 64 ->
// 8x8 grid of 64x64 base blocks per (b,c) image.
#define WW 512
#define IMG_F 262144            // 512*512 floats per (b,c)
#define BC 48                   // 16*3
#define NQB 12288               // 48 * 64 blocks * 4 quarter-blocks
#define TOTAL_PIX 12582912.0f   // 16*3*512*512

// Kernel 1: quarter-block (16 rows x 64 cols) sums of |n-a| and |a-p|.
// grid = 12288 workgroups x 256 threads; each thread: exactly one float4
// per input (3 independent loads). Max TLP, tiny tail.
__global__ __launch_bounds__(256) void hd_qblock_sums(
    const float* __restrict__ a, const float* __restrict__ p,
    const float* __restrict__ n,
    float* __restrict__ part_na, float* __restrict__ part_ap)
{
    const int wg  = blockIdx.x;          // 0..12287 = (bc, blk, q)
    const int bc  = wg >> 8;
    const int blk = (wg >> 2) & 63;
    const int q   = wg & 3;
    const int bi = blk >> 3, bj = blk & 7;
    const int tid = threadIdx.x;

    const int row = bi * 64 + q * 16 + (tid >> 4);
    const int col = bj * 64 + ((tid & 15) << 2);
    const size_t idx = (size_t)bc * IMG_F + (size_t)row * WW + col;

    float4 va = *(const float4*)(a + idx);
    float4 vp = *(const float4*)(p + idx);
    float4 vn = *(const float4*)(n + idx);

    float s1 = fabsf(vn.x - va.x) + fabsf(vn.y - va.y)
             + fabsf(vn.z - va.z) + fabsf(vn.w - va.w);
    float s2 = fabsf(va.x - vp.x) + fabsf(va.y - vp.y)
             + fabsf(va.z - vp.z) + fabsf(va.w - vp.w);

    #pragma unroll
    for (int off = 32; off > 0; off >>= 1) {
        s1 += __shfl_xor(s1, off, 64);
        s2 += __shfl_xor(s2, off, 64);
    }
    __shared__ float r1[4], r2[4];
    const int wave = tid >> 6, lane = tid & 63;
    if (lane == 0) { r1[wave] = s1; r2[wave] = s2; }
    __syncthreads();
    if (tid == 0) {
        part_na[wg] = r1[0] + r1[1] + r1[2] + r1[3];
        part_ap[wg] = r2[0] + r2[1] + r2[2] + r2[3];
    }
}

// Kernel 2: finalize. One wave per (b,c); 64 lanes = the 8x8 block grid.
// Each lane sums its block's 4 quarter partials via one float4 load per
// array, then pure shuffle math. 1 block x 1024 threads, 16 waves x 3 rounds.
__global__ __launch_bounds__(1024) void hd_finalize(
    const float* __restrict__ part_na, const float* __restrict__ part_ap,
    float* __restrict__ out)
{
    const int tid  = threadIdx.x;
    const int w    = tid >> 6;        // wave 0..15
    const int lane = tid & 63;
    const int i = lane >> 3, j = lane & 7;
    __shared__ float partial[16];

    float acc = 0.f;
    #pragma unroll
    for (int it = 0; it < 3; ++it) {
        const int bc = w + it * 16;
        float4 q1 = *(const float4*)(part_na + (size_t)(bc * 64 + lane) * 4);
        float4 q2 = *(const float4*)(part_ap + (size_t)(bc * 64 + lane) * 4);
        float b  = (q1.x + q1.y) + (q1.z + q1.w);
        float bp = (q2.x + q2.y) + (q2.z + q2.w);
        // diff = sum over 8x8 grid
        float d = b;
        #pragma unroll
        for (int off = 32; off > 0; off >>= 1) d += __shfl_xor(d, off, 64);
        // window value wv[i][j], defined for i,j<7 (else 0)
        float b_r  = __shfl(b, lane + 8, 64);   // blk[i+1][j]
        float b_c  = __shfl(b, lane + 1, 64);   // blk[i][j+1]
        float b_rc = __shfl(b, lane + 9, 64);   // blk[i+1][j+1]
        float wv = (i < 7 && j < 7) ? (b + b_r + b_c + b_rc) / d : 0.f;
        // overlap-add: mb[i][j] = wv[i][j] + wv[i-1][j] + wv[i][j-1] + wv[i-1][j-1]
        float wv_u  = __shfl(wv, lane - 8, 64);
        float wv_l  = __shfl(wv, lane - 1, 64);
        float wv_ul = __shfl(wv, lane - 9, 64);
        float mb = wv;
        if (i > 0)          mb += wv_u;
        if (j > 0)          mb += wv_l;
        if (i > 0 && j > 0) mb += wv_ul;
        const int ci = (i == 0 || i == 7) ? 1 : 2;
        const int cj = (j == 0 || j == 7) ? 1 : 2;
        acc += (mb / (float)(ci * cj)) * bp;
    }

    #pragma unroll
    for (int off = 32; off > 0; off >>= 1) acc += __shfl_xor(acc, off, 64);
    if (lane == 0) partial[w] = acc;
    __syncthreads();
    if (tid == 0) {
        float s = 0.f;
        #pragma unroll
        for (int k = 0; k < 16; ++k) s += partial[k];
        out[0] = s / TOTAL_PIX;
    }
}

extern "C" void kernel_launch(void* const* d_in, const int* in_sizes, int n_in,
                              void* d_out, int out_size, void* d_ws, size_t ws_size,
                              hipStream_t stream) {
    const float* a = (const float*)d_in[0];
    const float* p = (const float*)d_in[1];
    const float* n = (const float*)d_in[2];
    float* part_na = (float*)d_ws;                 // 12288 floats
    float* part_ap = part_na + NQB;                // 12288 floats

    hd_qblock_sums<<<NQB, 256, 0, stream>>>(a, p, n, part_na, part_ap);
    hd_finalize<<<1, 1024, 0, stream>>>(part_na, part_ap, (float*)d_out);
}